// Round 1
// baseline (295.855 us; speedup 1.0000x reference)
//
#include <hip/hip_runtime.h>
#include <hip/hip_bf16.h>

typedef __attribute__((ext_vector_type(8))) short short8;
typedef __attribute__((ext_vector_type(4))) float f32x4;

#define B_  8
#define T_  2048
#define C_  768
#define H_  64
#define M_  (B_ * T_)   // 16384 rows

static __device__ __forceinline__ unsigned short f2bf(float f) {
    __hip_bfloat16 h = __float2bfloat16(f);
    return *reinterpret_cast<unsigned short*>(&h);
}

static __device__ __forceinline__ short8 make_frag(const unsigned short* p0, const unsigned short* p1) {
    const ushort4 a = *reinterpret_cast<const ushort4*>(p0);
    const ushort4 b = *reinterpret_cast<const ushort4*>(p1);
    short8 r;
    r[0] = (short)a.x; r[1] = (short)a.y; r[2] = (short)a.z; r[3] = (short)a.w;
    r[4] = (short)b.x; r[5] = (short)b.y; r[6] = (short)b.z; r[7] = (short)b.w;
    return r;
}

// ---------------------------------------------------------------------------
// Kernel 1: fused QKV projection.  qkv[0]=Q, qkv[1]=K, qkv[2]=V, each
// [M_ x 64] bf16 row-major.  One block = 64 rows x 192 cols.
// ---------------------------------------------------------------------------
__global__ __launch_bounds__(256) void proj_kernel(
    const float* __restrict__ x,
    const float* __restrict__ Wq, const float* __restrict__ Wk, const float* __restrict__ Wv,
    unsigned short* __restrict__ qkv) {

    __shared__ unsigned short Al[64 * 32];        // x tile, [row][k]
    __shared__ unsigned short Bl[3][64 * 32];     // W^T tiles, [h][k]

    const int tid = threadIdx.x;
    const int w  = tid >> 6;      // wave 0..3
    const int l  = tid & 63;
    const int lg = l >> 4;        // lane group 0..3
    const int lc = l & 15;
    const int row0 = blockIdx.x * 64;

    const float* Wmat[3] = {Wq, Wk, Wv};

    f32x4 acc[3][4];
#pragma unroll
    for (int m = 0; m < 3; ++m)
#pragma unroll
        for (int t = 0; t < 4; ++t) acc[m][t] = (f32x4)0.f;

    for (int kk = 0; kk < C_ / 32; ++kk) {
        __syncthreads();
        // ---- stage A: 64 rows x 32 k of x, converted to bf16
        {
            const int r  = tid >> 2;
            const int q4 = tid & 3;
            const float* xp = x + (size_t)(row0 + r) * C_ + kk * 32 + q4 * 8;
            float4 f0 = *reinterpret_cast<const float4*>(xp);
            float4 f1 = *reinterpret_cast<const float4*>(xp + 4);
            unsigned short* d = &Al[r * 32 + q4 * 8];
            d[0] = f2bf(f0.x); d[1] = f2bf(f0.y); d[2] = f2bf(f0.z); d[3] = f2bf(f0.w);
            d[4] = f2bf(f1.x); d[5] = f2bf(f1.y); d[6] = f2bf(f1.z); d[7] = f2bf(f1.w);
        }
        // ---- stage B: W chunk 32k x 64h transposed into [h][k]
#pragma unroll
        for (int m = 0; m < 3; ++m) {
#pragma unroll
            for (int rep = 0; rep < 2; ++rep) {
                const int o = rep * 1024 + tid * 4;
                const int c = o >> 6;        // 0..31 (k within chunk)
                const int h = o & 63;        // multiple of 4
                float4 f = *reinterpret_cast<const float4*>(&Wmat[m][(size_t)(kk * 32 + c) * H_ + h]);
                Bl[m][(h + 0) * 32 + c] = f2bf(f.x);
                Bl[m][(h + 1) * 32 + c] = f2bf(f.y);
                Bl[m][(h + 2) * 32 + c] = f2bf(f.z);
                Bl[m][(h + 3) * 32 + c] = f2bf(f.w);
            }
        }
        __syncthreads();

        // ---- MFMA: wave w owns rows w*16..w*16+15, all 192 cols
        const short8 af = make_frag(&Al[(w * 16 + lc) * 32 + lg * 4],
                                    &Al[(w * 16 + lc) * 32 + lg * 4 + 16]);
#pragma unroll
        for (int m = 0; m < 3; ++m) {
#pragma unroll
            for (int ht = 0; ht < 4; ++ht) {
                const short8 bf = make_frag(&Bl[m][(ht * 16 + lc) * 32 + lg * 4],
                                            &Bl[m][(ht * 16 + lc) * 32 + lg * 4 + 16]);
                acc[m][ht] = __builtin_amdgcn_mfma_f32_16x16x32_bf16(af, bf, acc[m][ht], 0, 0, 0);
            }
        }
    }

    // ---- epilogue: write bf16 q/k/v
#pragma unroll
    for (int m = 0; m < 3; ++m)
#pragma unroll
        for (int ht = 0; ht < 4; ++ht)
#pragma unroll
            for (int r = 0; r < 4; ++r) {
                const int grow = row0 + w * 16 + lg * 4 + r;
                qkv[(size_t)m * (M_ * H_) + (size_t)grow * H_ + ht * 16 + lc] = f2bf(acc[m][ht][r]);
            }
}

// ---------------------------------------------------------------------------
// Kernel 2: causal flash attention.  One block per (batch, 64-row Q tile).
// 4 waves; wave w owns Q rows w*16..w*16+15 of the tile.
// ---------------------------------------------------------------------------
__global__ __launch_bounds__(256) void attn_kernel(
    const unsigned short* __restrict__ qkv, float* __restrict__ out) {

    const int b  = blockIdx.x >> 5;
    const int qt = blockIdx.x & 31;
    const int tid = threadIdx.x;
    const int w  = tid >> 6;
    const int l  = tid & 63;
    const int lg = l >> 4;
    const int lc = l & 15;

    __shared__ unsigned short Kl[64 * 64];        // K tile [s][h]
    __shared__ unsigned short Vt[64 * 64];        // V tile transposed [h][s]
    __shared__ unsigned short Pl[4][16 * 64];     // per-wave P [qrow][s]

    const unsigned short* Qg = qkv;
    const unsigned short* Kg = qkv + (size_t)M_ * H_;
    const unsigned short* Vg = qkv + (size_t)2 * M_ * H_;

    // Q fragments held in registers for the whole kernel
    const unsigned short* qrow = Qg + (size_t)(b * T_ + qt * 64 + w * 16 + lc) * H_;
    short8 qf[2];
#pragma unroll
    for (int ks = 0; ks < 2; ++ks)
        qf[ks] = make_frag(qrow + ks * 32 + lg * 4, qrow + ks * 32 + lg * 4 + 16);

    float m[4], lsum[4];
    f32x4 o[4];
#pragma unroll
    for (int r = 0; r < 4; ++r) { m[r] = -1e30f; lsum[r] = 0.f; }
#pragma unroll
    for (int t = 0; t < 4; ++t) o[t] = (f32x4)0.f;

    const int q_row_g = qt * 64 + w * 16 + lg * 4;   // + r

    for (int kv = 0; kv <= qt; ++kv) {
        __syncthreads();
        // ---- stage K [s][h] and V^T [h][s]
#pragma unroll
        for (int rep = 0; rep < 2; ++rep) {
            const int idx = rep * 256 + tid;          // 0..511
            const int s  = idx >> 3;
            const int h0 = (idx & 7) * 8;
            const size_t g = (size_t)(b * T_ + kv * 64 + s) * H_ + h0;
            ushort4 k0 = *reinterpret_cast<const ushort4*>(&Kg[g]);
            ushort4 k1 = *reinterpret_cast<const ushort4*>(&Kg[g + 4]);
            *reinterpret_cast<ushort4*>(&Kl[s * 64 + h0])     = k0;
            *reinterpret_cast<ushort4*>(&Kl[s * 64 + h0 + 4]) = k1;
            ushort4 v0 = *reinterpret_cast<const ushort4*>(&Vg[g]);
            ushort4 v1 = *reinterpret_cast<const ushort4*>(&Vg[g + 4]);
            Vt[(h0 + 0) * 64 + s] = v0.x; Vt[(h0 + 1) * 64 + s] = v0.y;
            Vt[(h0 + 2) * 64 + s] = v0.z; Vt[(h0 + 3) * 64 + s] = v0.w;
            Vt[(h0 + 4) * 64 + s] = v1.x; Vt[(h0 + 5) * 64 + s] = v1.y;
            Vt[(h0 + 6) * 64 + s] = v1.z; Vt[(h0 + 7) * 64 + s] = v1.w;
        }
        __syncthreads();

        // ---- S = (Q K^T) * scale
        f32x4 sfrag[4];
#pragma unroll
        for (int st = 0; st < 4; ++st) {
            f32x4 accs = (f32x4)0.f;
#pragma unroll
            for (int ks = 0; ks < 2; ++ks) {
                const short8 bf = make_frag(&Kl[(st * 16 + lc) * 64 + ks * 32 + lg * 4],
                                            &Kl[(st * 16 + lc) * 64 + ks * 32 + lg * 4 + 16]);
                accs = __builtin_amdgcn_mfma_f32_16x16x32_bf16(qf[ks], bf, accs, 0, 0, 0);
            }
            sfrag[st] = accs;
        }

        // ---- online softmax (rows 4*lg + r, cols st*16 + lc)
        const bool diag = (kv == qt);
        float p[4][4];
#pragma unroll
        for (int r = 0; r < 4; ++r) {
            float mx = -1e30f;
#pragma unroll
            for (int st = 0; st < 4; ++st) {
                float sv = sfrag[st][r] * 0.125f;
                if (diag && (kv * 64 + st * 16 + lc) > (q_row_g + r)) sv = -1e30f;
                p[r][st] = sv;
                mx = fmaxf(mx, sv);
            }
#pragma unroll
            for (int d = 1; d < 16; d <<= 1) mx = fmaxf(mx, __shfl_xor(mx, d));

            const float mnew  = fmaxf(m[r], mx);
            const float alpha = expf(m[r] - mnew);
            float srow = 0.f;
#pragma unroll
            for (int st = 0; st < 4; ++st) {
                const float pv = expf(p[r][st] - mnew);
                p[r][st] = pv;
                srow += pv;
            }
#pragma unroll
            for (int d = 1; d < 16; d <<= 1) srow += __shfl_xor(srow, d);
            lsum[r] = lsum[r] * alpha + srow;
            m[r] = mnew;
#pragma unroll
            for (int ht = 0; ht < 4; ++ht) o[ht][r] *= alpha;
#pragma unroll
            for (int st = 0; st < 4; ++st)
                Pl[w][(lg * 4 + r) * 64 + st * 16 + lc] = f2bf(p[r][st]);
        }

        // ---- O += P V
#pragma unroll
        for (int ks = 0; ks < 2; ++ks) {
            const short8 pf = make_frag(&Pl[w][lc * 64 + ks * 32 + lg * 4],
                                        &Pl[w][lc * 64 + ks * 32 + lg * 4 + 16]);
#pragma unroll
            for (int ht = 0; ht < 4; ++ht) {
                const short8 vf = make_frag(&Vt[(ht * 16 + lc) * 64 + ks * 32 + lg * 4],
                                            &Vt[(ht * 16 + lc) * 64 + ks * 32 + lg * 4 + 16]);
                o[ht] = __builtin_amdgcn_mfma_f32_16x16x32_bf16(pf, vf, o[ht], 0, 0, 0);
            }
        }
    }

    // ---- epilogue
#pragma unroll
    for (int ht = 0; ht < 4; ++ht)
#pragma unroll
        for (int r = 0; r < 4; ++r) {
            const size_t oi = (size_t)(b * T_ + q_row_g + r) * H_ + ht * 16 + lc;
            out[oi] = o[ht][r] / lsum[r];
        }
}

extern "C" void kernel_launch(void* const* d_in, const int* in_sizes, int n_in,
                              void* d_out, int out_size, void* d_ws, size_t ws_size,
                              hipStream_t stream) {
    const float* x  = (const float*)d_in[0];
    const float* Wk = (const float*)d_in[1];
    const float* Wq = (const float*)d_in[2];
    const float* Wv = (const float*)d_in[3];
    unsigned short* qkv = (unsigned short*)d_ws;   // 3 * 16384 * 64 bf16 = 6.3 MB

    proj_kernel<<<dim3(M_ / 64), dim3(256), 0, stream>>>(x, Wq, Wk, Wv, qkv);
    attn_kernel<<<dim3(B_ * (T_ / 64)), dim3(256), 0, stream>>>(qkv, (float*)d_out);
}

// Round 2
// 134.719 us; speedup vs baseline: 2.1961x; 2.1961x over previous
//
#include <hip/hip_runtime.h>
#include <hip/hip_bf16.h>

typedef __attribute__((ext_vector_type(8))) short short8;
typedef __attribute__((ext_vector_type(4))) float f32x4;

#define B_  8
#define T_  2048
#define C_  768
#define H_  64
#define M_  (B_ * T_)   // 16384 rows

static __device__ __forceinline__ unsigned short f2bf(float f) {
    __hip_bfloat16 h = __float2bfloat16(f);
    return *reinterpret_cast<unsigned short*>(&h);
}

static __device__ __forceinline__ short8 make_frag(const unsigned short* p0, const unsigned short* p1) {
    const ushort4 a = *reinterpret_cast<const ushort4*>(p0);
    const ushort4 b = *reinterpret_cast<const ushort4*>(p1);
    short8 r;
    r[0] = (short)a.x; r[1] = (short)a.y; r[2] = (short)a.z; r[3] = (short)a.w;
    r[4] = (short)b.x; r[5] = (short)b.y; r[6] = (short)b.z; r[7] = (short)b.w;
    return r;
}

// XOR swizzle for LDS tiles with 64-ushort (128 B) rows: permute the 16 B
// chunk index with row&7 so column-slice reads spread across banks.
// u = ushort offset within the row (frag reads use u ≡ 0 mod 4).
static __device__ __forceinline__ int swz(int row, int u) {
    return row * 64 + ((((u) >> 3) ^ (row & 7)) << 3) + (u & 7);
}

// ---------------------------------------------------------------------------
// Kernel 1: fused QKV projection (unchanged from round 1).
// ---------------------------------------------------------------------------
__global__ __launch_bounds__(256) void proj_kernel(
    const float* __restrict__ x,
    const float* __restrict__ Wq, const float* __restrict__ Wk, const float* __restrict__ Wv,
    unsigned short* __restrict__ qkv) {

    __shared__ unsigned short Al[64 * 32];        // x tile, [row][k]
    __shared__ unsigned short Bl[3][64 * 32];     // W^T tiles, [h][k]

    const int tid = threadIdx.x;
    const int w  = tid >> 6;      // wave 0..3
    const int l  = tid & 63;
    const int lg = l >> 4;        // lane group 0..3
    const int lc = l & 15;
    const int row0 = blockIdx.x * 64;

    const float* Wmat[3] = {Wq, Wk, Wv};

    f32x4 acc[3][4];
#pragma unroll
    for (int m = 0; m < 3; ++m)
#pragma unroll
        for (int t = 0; t < 4; ++t) acc[m][t] = (f32x4)0.f;

    for (int kk = 0; kk < C_ / 32; ++kk) {
        __syncthreads();
        {
            const int r  = tid >> 2;
            const int q4 = tid & 3;
            const float* xp = x + (size_t)(row0 + r) * C_ + kk * 32 + q4 * 8;
            float4 f0 = *reinterpret_cast<const float4*>(xp);
            float4 f1 = *reinterpret_cast<const float4*>(xp + 4);
            unsigned short* d = &Al[r * 32 + q4 * 8];
            d[0] = f2bf(f0.x); d[1] = f2bf(f0.y); d[2] = f2bf(f0.z); d[3] = f2bf(f0.w);
            d[4] = f2bf(f1.x); d[5] = f2bf(f1.y); d[6] = f2bf(f1.z); d[7] = f2bf(f1.w);
        }
#pragma unroll
        for (int m = 0; m < 3; ++m) {
#pragma unroll
            for (int rep = 0; rep < 2; ++rep) {
                const int o = rep * 1024 + tid * 4;
                const int c = o >> 6;
                const int h = o & 63;
                float4 f = *reinterpret_cast<const float4*>(&Wmat[m][(size_t)(kk * 32 + c) * H_ + h]);
                Bl[m][(h + 0) * 32 + c] = f2bf(f.x);
                Bl[m][(h + 1) * 32 + c] = f2bf(f.y);
                Bl[m][(h + 2) * 32 + c] = f2bf(f.z);
                Bl[m][(h + 3) * 32 + c] = f2bf(f.w);
            }
        }
        __syncthreads();

        const short8 af = make_frag(&Al[(w * 16 + lc) * 32 + lg * 4],
                                    &Al[(w * 16 + lc) * 32 + lg * 4 + 16]);
#pragma unroll
        for (int m = 0; m < 3; ++m) {
#pragma unroll
            for (int ht = 0; ht < 4; ++ht) {
                const short8 bf = make_frag(&Bl[m][(ht * 16 + lc) * 32 + lg * 4],
                                            &Bl[m][(ht * 16 + lc) * 32 + lg * 4 + 16]);
                acc[m][ht] = __builtin_amdgcn_mfma_f32_16x16x32_bf16(af, bf, acc[m][ht], 0, 0, 0);
            }
        }
    }

#pragma unroll
    for (int m = 0; m < 3; ++m)
#pragma unroll
        for (int ht = 0; ht < 4; ++ht)
#pragma unroll
            for (int r = 0; r < 4; ++r) {
                const int grow = row0 + w * 16 + lg * 4 + r;
                qkv[(size_t)m * (M_ * H_) + (size_t)grow * H_ + ht * 16 + lc] = f2bf(acc[m][ht][r]);
            }
}

// ---------------------------------------------------------------------------
// Segment bookkeeping for split-KV flash attention (KV tiles of 64 rows).
// SEG = max KV tiles per segment.  SEG=8: segs/qt = qt/8+1 (80 per batch).
// SEG=32: one segment per q-tile (32 per batch).
// Each segment writes: O[64][64] fp32 (unnormalized), m[64], l[64] -> 4224 floats.
// ---------------------------------------------------------------------------
#define SEG_FLOATS 4224

template<int SEG>
static __device__ __forceinline__ int segs_per_batch() { return SEG == 32 ? 32 : 80; }

template<int SEG>
static __device__ __forceinline__ void decode_seg(int r, int& qt, int& seg) {
    if (SEG == 32) { qt = r; seg = 0; return; }
    if (r < 8)       { qt = r;                seg = 0; }
    else if (r < 24) { qt = 8  + (r - 8) / 2; seg = (r - 8) & 1; }
    else if (r < 48) { qt = 16 + (r - 24) / 3; seg = (r - 24) % 3; }
    else             { qt = 24 + (r - 48) / 4; seg = (r - 48) & 3; }
}

template<int SEG>
static __device__ __forceinline__ int seg_prefix(int qt) {
    if (SEG == 32) return qt;
    if (qt < 8)  return qt;
    if (qt < 16) return 8  + 2 * (qt - 8);
    if (qt < 24) return 24 + 3 * (qt - 16);
    return 48 + 4 * (qt - 24);
}

// ---------------------------------------------------------------------------
// Kernel 2a: partial causal flash attention over one KV segment.
// Block = 256 threads (4 waves), Q tile = 64 rows.  Swizzled LDS.
// ---------------------------------------------------------------------------
template<int SEG>
__global__ __launch_bounds__(256) void attn_partial(
    const unsigned short* __restrict__ qkv, float* __restrict__ part) {

    const int spb = segs_per_batch<SEG>();
    const int b   = blockIdx.x / spb;
    const int r_  = blockIdx.x % spb;
    int qt, seg;
    decode_seg<SEG>(r_, qt, seg);

    const int tid = threadIdx.x;
    const int w  = tid >> 6;
    const int l  = tid & 63;
    const int lg = l >> 4;
    const int lc = l & 15;

    __shared__ unsigned short Kl[64 * 64];        // K tile [s][h], swizzled
    __shared__ unsigned short Vt[64 * 64];        // V^T tile [h][s], swizzled
    __shared__ unsigned short Pl[4][16 * 64];     // per-wave P [q][s], swizzled

    const unsigned short* Qg = qkv;
    const unsigned short* Kg = qkv + (size_t)M_ * H_;
    const unsigned short* Vg = qkv + (size_t)2 * M_ * H_;

    const unsigned short* qrow = Qg + (size_t)(b * T_ + qt * 64 + w * 16 + lc) * H_;
    short8 qf[2];
#pragma unroll
    for (int ks = 0; ks < 2; ++ks)
        qf[ks] = make_frag(qrow + ks * 32 + lg * 4, qrow + ks * 32 + lg * 4 + 16);

    float m[4], lsum[4];
    f32x4 o[4];
#pragma unroll
    for (int r = 0; r < 4; ++r) { m[r] = -1e30f; lsum[r] = 0.f; }
#pragma unroll
    for (int t = 0; t < 4; ++t) o[t] = (f32x4)0.f;

    const int q_row_g = qt * 64 + w * 16 + lg * 4;   // + r

    const int kv_beg = seg * SEG;
    const int kv_end = min(kv_beg + SEG, qt + 1);

    for (int kv = kv_beg; kv < kv_end; ++kv) {
        __syncthreads();
        // ---- stage K: 16B chunks, swizzled dest
#pragma unroll
        for (int rep = 0; rep < 2; ++rep) {
            const int idx = rep * 256 + tid;          // 0..511
            const int s   = idx >> 3;
            const int c16 = idx & 7;
            const size_t g = (size_t)(b * T_ + kv * 64 + s) * H_ + c16 * 8;
            short8 kvec = *reinterpret_cast<const short8*>(&Kg[g]);
            *reinterpret_cast<short8*>(&Kl[s * 64 + ((c16 ^ (s & 7)) << 3)]) = kvec;
        }
        // ---- stage V^T: paired-row u32 stores, swizzled dest
#pragma unroll
        for (int rep = 0; rep < 2; ++rep) {
            const int idx = rep * 256 + tid;          // 0..511
            const int s2  = idx >> 4;                 // row pair 0..31
            const int h0  = (idx & 15) * 4;
            const int s   = 2 * s2;
            const size_t g = (size_t)(b * T_ + kv * 64 + s) * H_ + h0;
            ushort4 v0 = *reinterpret_cast<const ushort4*>(&Vg[g]);
            ushort4 v1 = *reinterpret_cast<const ushort4*>(&Vg[g + H_]);
#pragma unroll
            for (int j = 0; j < 4; ++j) {
                const int h = h0 + j;
                unsigned int pk = (unsigned int)(&v0.x)[j] | ((unsigned int)(&v1.x)[j] << 16);
                *reinterpret_cast<unsigned int*>(&Vt[swz(h, s)]) = pk;
            }
        }
        __syncthreads();

        // ---- S = (Q K^T) * scale
        f32x4 sfrag[4];
#pragma unroll
        for (int st = 0; st < 4; ++st) {
            f32x4 accs = (f32x4)0.f;
#pragma unroll
            for (int ks = 0; ks < 2; ++ks) {
                const short8 bf = make_frag(&Kl[swz(st * 16 + lc, ks * 32 + lg * 4)],
                                            &Kl[swz(st * 16 + lc, ks * 32 + lg * 4 + 16)]);
                accs = __builtin_amdgcn_mfma_f32_16x16x32_bf16(qf[ks], bf, accs, 0, 0, 0);
            }
            sfrag[st] = accs;
        }

        // ---- online softmax
        const bool diag = (kv == qt);
        float p[4][4];
#pragma unroll
        for (int r = 0; r < 4; ++r) {
            float mx = -1e30f;
#pragma unroll
            for (int st = 0; st < 4; ++st) {
                float sv = sfrag[st][r] * 0.125f;
                if (diag && (kv * 64 + st * 16 + lc) > (q_row_g + r)) sv = -1e30f;
                p[r][st] = sv;
                mx = fmaxf(mx, sv);
            }
#pragma unroll
            for (int d = 1; d < 16; d <<= 1) mx = fmaxf(mx, __shfl_xor(mx, d));

            const float mnew  = fmaxf(m[r], mx);
            const float alpha = expf(m[r] - mnew);
            float srow = 0.f;
#pragma unroll
            for (int st = 0; st < 4; ++st) {
                const float pv = expf(p[r][st] - mnew);
                p[r][st] = pv;
                srow += pv;
            }
#pragma unroll
            for (int d = 1; d < 16; d <<= 1) srow += __shfl_xor(srow, d);
            lsum[r] = lsum[r] * alpha + srow;
            m[r] = mnew;
#pragma unroll
            for (int ht = 0; ht < 4; ++ht) o[ht][r] *= alpha;
#pragma unroll
            for (int st = 0; st < 4; ++st)
                Pl[w][swz(lg * 4 + r, st * 16 + lc)] = f2bf(p[r][st]);
        }

        // ---- O += P V
#pragma unroll
        for (int ks = 0; ks < 2; ++ks) {
            const short8 pf = make_frag(&Pl[w][swz(lc, ks * 32 + lg * 4)],
                                        &Pl[w][swz(lc, ks * 32 + lg * 4 + 16)]);
#pragma unroll
            for (int ht = 0; ht < 4; ++ht) {
                const short8 vf = make_frag(&Vt[swz(ht * 16 + lc, ks * 32 + lg * 4)],
                                            &Vt[swz(ht * 16 + lc, ks * 32 + lg * 4 + 16)]);
                o[ht] = __builtin_amdgcn_mfma_f32_16x16x32_bf16(pf, vf, o[ht], 0, 0, 0);
            }
        }
    }

    // ---- write partial (unnormalized O, m, l)
    float* base = part + (size_t)blockIdx.x * SEG_FLOATS;
#pragma unroll
    for (int ht = 0; ht < 4; ++ht)
#pragma unroll
        for (int r = 0; r < 4; ++r)
            base[(w * 16 + lg * 4 + r) * 64 + ht * 16 + lc] = o[ht][r];
    if (lc == 0) {
#pragma unroll
        for (int r = 0; r < 4; ++r) {
            base[4096 + w * 16 + lg * 4 + r] = m[r];
            base[4160 + w * 16 + lg * 4 + r] = lsum[r];
        }
    }
}

// ---------------------------------------------------------------------------
// Kernel 2b: merge segments, normalize, write output.
// Grid = B * 32 blocks (one per q-tile), 256 threads.
// ---------------------------------------------------------------------------
template<int SEG>
__global__ __launch_bounds__(256) void attn_merge(
    const float* __restrict__ part, float* __restrict__ out) {

    const int b  = blockIdx.x >> 5;
    const int qt = blockIdx.x & 31;
    const int nseg = (SEG == 32) ? 1 : (qt / 8 + 1);
    const int spb  = segs_per_batch<SEG>();
    const float* base0 = part + (size_t)(b * spb + seg_prefix<SEG>(qt)) * SEG_FLOATS;

    const int tid = threadIdx.x;
    const int row = tid >> 2;
    const int c0  = (tid & 3) * 16;

    float M = -1e30f;
    for (int s = 0; s < nseg; ++s)
        M = fmaxf(M, base0[(size_t)s * SEG_FLOATS + 4096 + row]);

    float L = 0.f;
    f32x4 acc[4];
#pragma unroll
    for (int k = 0; k < 4; ++k) acc[k] = (f32x4)0.f;

    for (int s = 0; s < nseg; ++s) {
        const float* sb = base0 + (size_t)s * SEG_FLOATS;
        const float wsc = expf(sb[4096 + row] - M);
        L += sb[4160 + row] * wsc;
#pragma unroll
        for (int k = 0; k < 4; ++k) {
            const f32x4 ov = *reinterpret_cast<const f32x4*>(&sb[row * 64 + c0 + 4 * k]);
            acc[k] += ov * wsc;
        }
    }
    const float inv = 1.f / L;
    float* op = out + (size_t)(b * T_ + qt * 64 + row) * H_ + c0;
#pragma unroll
    for (int k = 0; k < 4; ++k)
        *reinterpret_cast<f32x4*>(&op[4 * k]) = acc[k] * inv;
}

// ---------------------------------------------------------------------------
// Fallback: round-1 single-pass attention (used only if ws too small).
// ---------------------------------------------------------------------------
__global__ __launch_bounds__(256) void attn_kernel(
    const unsigned short* __restrict__ qkv, float* __restrict__ out) {

    const int b  = blockIdx.x >> 5;
    const int qt = blockIdx.x & 31;
    const int tid = threadIdx.x;
    const int w  = tid >> 6;
    const int l  = tid & 63;
    const int lg = l >> 4;
    const int lc = l & 15;

    __shared__ unsigned short Kl[64 * 64];
    __shared__ unsigned short Vt[64 * 64];
    __shared__ unsigned short Pl[4][16 * 64];

    const unsigned short* Qg = qkv;
    const unsigned short* Kg = qkv + (size_t)M_ * H_;
    const unsigned short* Vg = qkv + (size_t)2 * M_ * H_;

    const unsigned short* qrow = Qg + (size_t)(b * T_ + qt * 64 + w * 16 + lc) * H_;
    short8 qf[2];
#pragma unroll
    for (int ks = 0; ks < 2; ++ks)
        qf[ks] = make_frag(qrow + ks * 32 + lg * 4, qrow + ks * 32 + lg * 4 + 16);

    float m[4], lsum[4];
    f32x4 o[4];
#pragma unroll
    for (int r = 0; r < 4; ++r) { m[r] = -1e30f; lsum[r] = 0.f; }
#pragma unroll
    for (int t = 0; t < 4; ++t) o[t] = (f32x4)0.f;

    const int q_row_g = qt * 64 + w * 16 + lg * 4;

    for (int kv = 0; kv <= qt; ++kv) {
        __syncthreads();
#pragma unroll
        for (int rep = 0; rep < 2; ++rep) {
            const int idx = rep * 256 + tid;
            const int s   = idx >> 3;
            const int c16 = idx & 7;
            const size_t g = (size_t)(b * T_ + kv * 64 + s) * H_ + c16 * 8;
            short8 kvec = *reinterpret_cast<const short8*>(&Kg[g]);
            *reinterpret_cast<short8*>(&Kl[s * 64 + ((c16 ^ (s & 7)) << 3)]) = kvec;
        }
#pragma unroll
        for (int rep = 0; rep < 2; ++rep) {
            const int idx = rep * 256 + tid;
            const int s2  = idx >> 4;
            const int h0  = (idx & 15) * 4;
            const int s   = 2 * s2;
            const size_t g = (size_t)(b * T_ + kv * 64 + s) * H_ + h0;
            ushort4 v0 = *reinterpret_cast<const ushort4*>(&Vg[g]);
            ushort4 v1 = *reinterpret_cast<const ushort4*>(&Vg[g + H_]);
#pragma unroll
            for (int j = 0; j < 4; ++j) {
                const int h = h0 + j;
                unsigned int pk = (unsigned int)(&v0.x)[j] | ((unsigned int)(&v1.x)[j] << 16);
                *reinterpret_cast<unsigned int*>(&Vt[swz(h, s)]) = pk;
            }
        }
        __syncthreads();

        f32x4 sfrag[4];
#pragma unroll
        for (int st = 0; st < 4; ++st) {
            f32x4 accs = (f32x4)0.f;
#pragma unroll
            for (int ks = 0; ks < 2; ++ks) {
                const short8 bf = make_frag(&Kl[swz(st * 16 + lc, ks * 32 + lg * 4)],
                                            &Kl[swz(st * 16 + lc, ks * 32 + lg * 4 + 16)]);
                accs = __builtin_amdgcn_mfma_f32_16x16x32_bf16(qf[ks], bf, accs, 0, 0, 0);
            }
            sfrag[st] = accs;
        }

        const bool diag = (kv == qt);
        float p[4][4];
#pragma unroll
        for (int r = 0; r < 4; ++r) {
            float mx = -1e30f;
#pragma unroll
            for (int st = 0; st < 4; ++st) {
                float sv = sfrag[st][r] * 0.125f;
                if (diag && (kv * 64 + st * 16 + lc) > (q_row_g + r)) sv = -1e30f;
                p[r][st] = sv;
                mx = fmaxf(mx, sv);
            }
#pragma unroll
            for (int d = 1; d < 16; d <<= 1) mx = fmaxf(mx, __shfl_xor(mx, d));

            const float mnew  = fmaxf(m[r], mx);
            const float alpha = expf(m[r] - mnew);
            float srow = 0.f;
#pragma unroll
            for (int st = 0; st < 4; ++st) {
                const float pv = expf(p[r][st] - mnew);
                p[r][st] = pv;
                srow += pv;
            }
#pragma unroll
            for (int d = 1; d < 16; d <<= 1) srow += __shfl_xor(srow, d);
            lsum[r] = lsum[r] * alpha + srow;
            m[r] = mnew;
#pragma unroll
            for (int ht = 0; ht < 4; ++ht) o[ht][r] *= alpha;
#pragma unroll
            for (int st = 0; st < 4; ++st)
                Pl[w][swz(lg * 4 + r, st * 16 + lc)] = f2bf(p[r][st]);
        }

#pragma unroll
        for (int ks = 0; ks < 2; ++ks) {
            const short8 pf = make_frag(&Pl[w][swz(lc, ks * 32 + lg * 4)],
                                        &Pl[w][swz(lc, ks * 32 + lg * 4 + 16)]);
#pragma unroll
            for (int ht = 0; ht < 4; ++ht) {
                const short8 vf = make_frag(&Vt[swz(ht * 16 + lc, ks * 32 + lg * 4)],
                                            &Vt[swz(ht * 16 + lc, ks * 32 + lg * 4 + 16)]);
                o[ht] = __builtin_amdgcn_mfma_f32_16x16x32_bf16(pf, vf, o[ht], 0, 0, 0);
            }
        }
    }

#pragma unroll
    for (int ht = 0; ht < 4; ++ht)
#pragma unroll
        for (int r = 0; r < 4; ++r) {
            const size_t oi = (size_t)(b * T_ + q_row_g + r) * H_ + ht * 16 + lc;
            out[oi] = o[ht][r] / lsum[r];
        }
}

extern "C" void kernel_launch(void* const* d_in, const int* in_sizes, int n_in,
                              void* d_out, int out_size, void* d_ws, size_t ws_size,
                              hipStream_t stream) {
    const float* x  = (const float*)d_in[0];
    const float* Wk = (const float*)d_in[1];
    const float* Wq = (const float*)d_in[2];
    const float* Wv = (const float*)d_in[3];
    unsigned short* qkv = (unsigned short*)d_ws;            // 6.29 MB bf16
    const size_t qkvB = (size_t)3 * M_ * H_ * 2;
    float* part = (float*)((char*)d_ws + qkvB);
    float* out  = (float*)d_out;

    proj_kernel<<<dim3(M_ / 64), dim3(256), 0, stream>>>(x, Wq, Wk, Wv, qkv);

    const size_t need8  = qkvB + (size_t)(B_ * 80) * SEG_FLOATS * 4;   // ~17.1 MB
    const size_t need32 = qkvB + (size_t)(B_ * 32) * SEG_FLOATS * 4;   // ~10.6 MB
    if (ws_size >= need8) {
        attn_partial<8><<<dim3(B_ * 80), dim3(256), 0, stream>>>(qkv, part);
        attn_merge<8><<<dim3(B_ * 32), dim3(256), 0, stream>>>(part, out);
    } else if (ws_size >= need32) {
        attn_partial<32><<<dim3(B_ * 32), dim3(256), 0, stream>>>(qkv, part);
        attn_merge<32><<<dim3(B_ * 32), dim3(256), 0, stream>>>(part, out);
    } else {
        attn_kernel<<<dim3(B_ * 32), dim3(256), 0, stream>>>(qkv, out);
    }
}

// Round 3
// 75.585 us; speedup vs baseline: 3.9142x; 1.7824x over previous
//
#include <hip/hip_runtime.h>
#include <hip/hip_bf16.h>

typedef __attribute__((ext_vector_type(8))) short short8;
typedef __attribute__((ext_vector_type(4))) float f32x4;

#define B_  8
#define T_  2048
#define C_  768
#define H_  64
#define M_  (B_ * T_)   // 16384 rows

static __device__ __forceinline__ unsigned short f2bf(float f) {
    __hip_bfloat16 h = __float2bfloat16(f);
    return *reinterpret_cast<unsigned short*>(&h);
}

static __device__ __forceinline__ short8 make_frag(const unsigned short* p0, const unsigned short* p1) {
    const ushort4 a = *reinterpret_cast<const ushort4*>(p0);
    const ushort4 b = *reinterpret_cast<const ushort4*>(p1);
    short8 r;
    r[0] = (short)a.x; r[1] = (short)a.y; r[2] = (short)a.z; r[3] = (short)a.w;
    r[4] = (short)b.x; r[5] = (short)b.y; r[6] = (short)b.z; r[7] = (short)b.w;
    return r;
}

// XOR swizzle for LDS tiles with 64-ushort (128 B) rows (attn kernels).
static __device__ __forceinline__ int swz(int row, int u) {
    return row * 64 + ((((u) >> 3) ^ (row & 7)) << 3) + (u & 7);
}

// ---------------------------------------------------------------------------
// Kernel 0: W -> Wt  (transpose + fp32->bf16).  Wt[192][768] bf16:
// rows 0..63 = Wq^T, 64..127 = Wk^T, 128..191 = Wv^T.
// Grid 144 x 256: thread -> (mat, h, 4 consecutive k).
// ---------------------------------------------------------------------------
__global__ __launch_bounds__(256) void prep_w(
    const float* __restrict__ Wq, const float* __restrict__ Wk, const float* __restrict__ Wv,
    unsigned short* __restrict__ Wt) {

    const int t   = threadIdx.x;
    const int mat = blockIdx.x / 48;
    const int kb  = blockIdx.x % 48;
    const int h   = t & 63;
    const int k0  = (kb * 4 + (t >> 6)) * 4;

    const float* Ws = (mat == 0) ? Wq : (mat == 1) ? Wk : Wv;
    ushort4 o;
    o.x = f2bf(Ws[(size_t)(k0 + 0) * H_ + h]);
    o.y = f2bf(Ws[(size_t)(k0 + 1) * H_ + h]);
    o.z = f2bf(Ws[(size_t)(k0 + 2) * H_ + h]);
    o.w = f2bf(Ws[(size_t)(k0 + 3) * H_ + h]);
    *reinterpret_cast<ushort4*>(&Wt[(size_t)(mat * 64 + h) * C_ + k0]) = o;
}

// ---------------------------------------------------------------------------
// Kernel 1: fused QKV projection, v3.
// Grid 256 x 256.  Block = 64 rows x 192 cols.  Wave w owns cols w*48..w*48+47
// (3 col-tiles) and ALL 64 rows (4 row-tiles) -> 12 acc tiles.
// Two K-phases of 384; x staged bf16 in LDS in fragment-order chunks with
// XOR placement (2-way max bank conflicts); B-frags read directly from
// L2-resident Wt with prefetch-1.  k within each 32-chunk is permuted
// (contiguous oct per lane-group) identically on A and B.
// ---------------------------------------------------------------------------
__global__ __launch_bounds__(256) void proj_kernel(
    const float* __restrict__ x, const unsigned short* __restrict__ Wt,
    unsigned short* __restrict__ qkv) {

    __shared__ unsigned short Als[4 * 12 * 512];   // 48 KB: [rt][kk][chunk*8]

    const int tid = threadIdx.x;
    const int w   = tid >> 6;
    const int l   = tid & 63;
    const int lg  = l >> 4;
    const int lc  = l & 15;
    const int row0 = blockIdx.x * 64;

    // staging coords
    const int sr  = tid >> 2;          // row 0..63
    const int so  = tid & 3;           // oct 0..3
    const int srt = sr >> 4;
    const int sr15 = sr & 15;
    const int sbase = (so * 16 + (sr15 ^ so)) * 8;   // chunk*8 (ushort units)

    f32x4 acc[4][3];
#pragma unroll
    for (int rt = 0; rt < 4; ++rt)
#pragma unroll
        for (int ct = 0; ct < 3; ++ct) acc[rt][ct] = (f32x4)0.f;

    // B address base: col = w*48 + ct*16 + lc
    const unsigned short* bbase[3];
#pragma unroll
    for (int ct = 0; ct < 3; ++ct)
        bbase[ct] = Wt + (size_t)(w * 48 + ct * 16 + lc) * C_ + lg * 8;

    for (int phase = 0; phase < 2; ++phase) {
        if (phase) __syncthreads();
        // ---- stage 64 rows x 384 k of x (grouped loads for deep MLP)
#pragma unroll
        for (int g = 0; g < 3; ++g) {
            float4 fa[4][2];
#pragma unroll
            for (int jj = 0; jj < 4; ++jj) {
                const int j = g * 4 + jj;
                const float* xp = x + (size_t)(row0 + sr) * C_ + phase * 384 + j * 32 + so * 8;
                fa[jj][0] = *reinterpret_cast<const float4*>(xp);
                fa[jj][1] = *reinterpret_cast<const float4*>(xp + 4);
            }
#pragma unroll
            for (int jj = 0; jj < 4; ++jj) {
                const int j = g * 4 + jj;
                short8 v;
                v[0] = (short)f2bf(fa[jj][0].x); v[1] = (short)f2bf(fa[jj][0].y);
                v[2] = (short)f2bf(fa[jj][0].z); v[3] = (short)f2bf(fa[jj][0].w);
                v[4] = (short)f2bf(fa[jj][1].x); v[5] = (short)f2bf(fa[jj][1].y);
                v[6] = (short)f2bf(fa[jj][1].z); v[7] = (short)f2bf(fa[jj][1].w);
                *reinterpret_cast<short8*>(&Als[(srt * 12 + j) * 512 + sbase]) = v;
            }
        }
        __syncthreads();

        // ---- compute 12 k-steps, B prefetch-1
        short8 bcur[3], bnxt[3];
#pragma unroll
        for (int ct = 0; ct < 3; ++ct)
            bcur[ct] = *reinterpret_cast<const short8*>(bbase[ct] + phase * 384);

#pragma unroll
        for (int kk = 0; kk < 12; ++kk) {
            if (kk < 11) {
#pragma unroll
                for (int ct = 0; ct < 3; ++ct)
                    bnxt[ct] = *reinterpret_cast<const short8*>(bbase[ct] + phase * 384 + (kk + 1) * 32);
            }
            short8 af[4];
#pragma unroll
            for (int rt = 0; rt < 4; ++rt)
                af[rt] = *reinterpret_cast<const short8*>(
                    &Als[(rt * 12 + kk) * 512 + (lg * 16 + (lc ^ lg)) * 8]);
#pragma unroll
            for (int rt = 0; rt < 4; ++rt)
#pragma unroll
                for (int ct = 0; ct < 3; ++ct)
                    acc[rt][ct] = __builtin_amdgcn_mfma_f32_16x16x32_bf16(af[rt], bcur[ct], acc[rt][ct], 0, 0, 0);
            if (kk < 11) {
#pragma unroll
                for (int ct = 0; ct < 3; ++ct) bcur[ct] = bnxt[ct];
            }
        }
    }

    // ---- epilogue: C/D layout col=lc, row=lg*4+j
#pragma unroll
    for (int ct = 0; ct < 3; ++ct) {
        const int col = w * 48 + ct * 16 + lc;
        const int mat = col >> 6;
        const int h   = col & 63;
#pragma unroll
        for (int rt = 0; rt < 4; ++rt)
#pragma unroll
            for (int j = 0; j < 4; ++j) {
                const int grow = row0 + rt * 16 + lg * 4 + j;
                qkv[(size_t)mat * (M_ * H_) + (size_t)grow * H_ + h] = f2bf(acc[rt][ct][j]);
            }
    }
}

// ---------------------------------------------------------------------------
// Segment bookkeeping for split-KV flash attention (KV tiles of 64 rows).
// ---------------------------------------------------------------------------
#define SEG_FLOATS 4224
#define LOG2E_SCALE 0.18033688011112042f   // 0.125 * log2(e)

template<int SEG>
static __device__ __forceinline__ int segs_per_batch() { return SEG == 32 ? 32 : 80; }

template<int SEG>
static __device__ __forceinline__ void decode_seg(int r, int& qt, int& seg) {
    if (SEG == 32) { qt = r; seg = 0; return; }
    if (r < 8)       { qt = r;                seg = 0; }
    else if (r < 24) { qt = 8  + (r - 8) / 2; seg = (r - 8) & 1; }
    else if (r < 48) { qt = 16 + (r - 24) / 3; seg = (r - 24) % 3; }
    else             { qt = 24 + (r - 48) / 4; seg = (r - 48) & 3; }
}

template<int SEG>
static __device__ __forceinline__ int seg_prefix(int qt) {
    if (SEG == 32) return qt;
    if (qt < 8)  return qt;
    if (qt < 16) return 8  + 2 * (qt - 8);
    if (qt < 24) return 24 + 3 * (qt - 16);
    return 48 + 4 * (qt - 24);
}

// ---------------------------------------------------------------------------
// Kernel 2a: partial causal flash attention over one KV segment.
// ---------------------------------------------------------------------------
template<int SEG>
__global__ __launch_bounds__(256) void attn_partial(
    const unsigned short* __restrict__ qkv, float* __restrict__ part) {

    const int spb = segs_per_batch<SEG>();
    const int b   = blockIdx.x / spb;
    const int r_  = blockIdx.x % spb;
    int qt, seg;
    decode_seg<SEG>(r_, qt, seg);

    const int tid = threadIdx.x;
    const int w  = tid >> 6;
    const int l  = tid & 63;
    const int lg = l >> 4;
    const int lc = l & 15;

    __shared__ unsigned short Kl[64 * 64];
    __shared__ unsigned short Vt[64 * 64];
    __shared__ unsigned short Pl[4][16 * 64];

    const unsigned short* Qg = qkv;
    const unsigned short* Kg = qkv + (size_t)M_ * H_;
    const unsigned short* Vg = qkv + (size_t)2 * M_ * H_;

    const unsigned short* qrow = Qg + (size_t)(b * T_ + qt * 64 + w * 16 + lc) * H_;
    short8 qf[2];
#pragma unroll
    for (int ks = 0; ks < 2; ++ks)
        qf[ks] = make_frag(qrow + ks * 32 + lg * 4, qrow + ks * 32 + lg * 4 + 16);

    float m[4], lsum[4];
    f32x4 o[4];
#pragma unroll
    for (int r = 0; r < 4; ++r) { m[r] = -1e30f; lsum[r] = 0.f; }
#pragma unroll
    for (int t = 0; t < 4; ++t) o[t] = (f32x4)0.f;

    const int q_row_g = qt * 64 + w * 16 + lg * 4;

    const int kv_beg = seg * SEG;
    const int kv_end = min(kv_beg + SEG, qt + 1);

    for (int kv = kv_beg; kv < kv_end; ++kv) {
        __syncthreads();
#pragma unroll
        for (int rep = 0; rep < 2; ++rep) {
            const int idx = rep * 256 + tid;
            const int s   = idx >> 3;
            const int c16 = idx & 7;
            const size_t g = (size_t)(b * T_ + kv * 64 + s) * H_ + c16 * 8;
            short8 kvec = *reinterpret_cast<const short8*>(&Kg[g]);
            *reinterpret_cast<short8*>(&Kl[s * 64 + ((c16 ^ (s & 7)) << 3)]) = kvec;
        }
#pragma unroll
        for (int rep = 0; rep < 2; ++rep) {
            const int idx = rep * 256 + tid;
            const int s2  = idx >> 4;
            const int h0  = (idx & 15) * 4;
            const int s   = 2 * s2;
            const size_t g = (size_t)(b * T_ + kv * 64 + s) * H_ + h0;
            ushort4 v0 = *reinterpret_cast<const ushort4*>(&Vg[g]);
            ushort4 v1 = *reinterpret_cast<const ushort4*>(&Vg[g + H_]);
#pragma unroll
            for (int j = 0; j < 4; ++j) {
                const int h = h0 + j;
                unsigned int pk = (unsigned int)(&v0.x)[j] | ((unsigned int)(&v1.x)[j] << 16);
                *reinterpret_cast<unsigned int*>(&Vt[swz(h, s)]) = pk;
            }
        }
        __syncthreads();

        f32x4 sfrag[4];
#pragma unroll
        for (int st = 0; st < 4; ++st) {
            f32x4 accs = (f32x4)0.f;
#pragma unroll
            for (int ks = 0; ks < 2; ++ks) {
                const short8 bf = make_frag(&Kl[swz(st * 16 + lc, ks * 32 + lg * 4)],
                                            &Kl[swz(st * 16 + lc, ks * 32 + lg * 4 + 16)]);
                accs = __builtin_amdgcn_mfma_f32_16x16x32_bf16(qf[ks], bf, accs, 0, 0, 0);
            }
            sfrag[st] = accs;
        }

        const bool diag = (kv == qt);
        float p[4][4];
#pragma unroll
        for (int r = 0; r < 4; ++r) {
            float mx = -1e30f;
#pragma unroll
            for (int st = 0; st < 4; ++st) {
                float sv = sfrag[st][r] * LOG2E_SCALE;
                if (diag && (kv * 64 + st * 16 + lc) > (q_row_g + r)) sv = -1e30f;
                p[r][st] = sv;
                mx = fmaxf(mx, sv);
            }
#pragma unroll
            for (int d = 1; d < 16; d <<= 1) mx = fmaxf(mx, __shfl_xor(mx, d));

            const float mnew  = fmaxf(m[r], mx);
            const float alpha = exp2f(m[r] - mnew);
            float srow = 0.f;
#pragma unroll
            for (int st = 0; st < 4; ++st) {
                const float pv = exp2f(p[r][st] - mnew);
                p[r][st] = pv;
                srow += pv;
            }
#pragma unroll
            for (int d = 1; d < 16; d <<= 1) srow += __shfl_xor(srow, d);
            lsum[r] = lsum[r] * alpha + srow;
            m[r] = mnew;
#pragma unroll
            for (int ht = 0; ht < 4; ++ht) o[ht][r] *= alpha;
#pragma unroll
            for (int st = 0; st < 4; ++st)
                Pl[w][swz(lg * 4 + r, st * 16 + lc)] = f2bf(p[r][st]);
        }

#pragma unroll
        for (int ks = 0; ks < 2; ++ks) {
            const short8 pf = make_frag(&Pl[w][swz(lc, ks * 32 + lg * 4)],
                                        &Pl[w][swz(lc, ks * 32 + lg * 4 + 16)]);
#pragma unroll
            for (int ht = 0; ht < 4; ++ht) {
                const short8 vf = make_frag(&Vt[swz(ht * 16 + lc, ks * 32 + lg * 4)],
                                            &Vt[swz(ht * 16 + lc, ks * 32 + lg * 4 + 16)]);
                o[ht] = __builtin_amdgcn_mfma_f32_16x16x32_bf16(pf, vf, o[ht], 0, 0, 0);
            }
        }
    }

    float* base = part + (size_t)blockIdx.x * SEG_FLOATS;
#pragma unroll
    for (int ht = 0; ht < 4; ++ht)
#pragma unroll
        for (int r = 0; r < 4; ++r)
            base[(w * 16 + lg * 4 + r) * 64 + ht * 16 + lc] = o[ht][r];
    if (lc == 0) {
#pragma unroll
        for (int r = 0; r < 4; ++r) {
            base[4096 + w * 16 + lg * 4 + r] = m[r];
            base[4160 + w * 16 + lg * 4 + r] = lsum[r];
        }
    }
}

// ---------------------------------------------------------------------------
// Kernel 2b: merge segments, normalize, write output.
// ---------------------------------------------------------------------------
template<int SEG>
__global__ __launch_bounds__(256) void attn_merge(
    const float* __restrict__ part, float* __restrict__ out) {

    const int b  = blockIdx.x >> 5;
    const int qt = blockIdx.x & 31;
    const int nseg = (SEG == 32) ? 1 : (qt / 8 + 1);
    const int spb  = segs_per_batch<SEG>();
    const float* base0 = part + (size_t)(b * spb + seg_prefix<SEG>(qt)) * SEG_FLOATS;

    const int tid = threadIdx.x;
    const int row = tid >> 2;
    const int c0  = (tid & 3) * 16;

    float M = -1e30f;
    for (int s = 0; s < nseg; ++s)
        M = fmaxf(M, base0[(size_t)s * SEG_FLOATS + 4096 + row]);

    float L = 0.f;
    f32x4 acc[4];
#pragma unroll
    for (int k = 0; k < 4; ++k) acc[k] = (f32x4)0.f;

    for (int s = 0; s < nseg; ++s) {
        const float* sb = base0 + (size_t)s * SEG_FLOATS;
        const float wsc = exp2f(sb[4096 + row] - M);
        L += sb[4160 + row] * wsc;
#pragma unroll
        for (int k = 0; k < 4; ++k) {
            const f32x4 ov = *reinterpret_cast<const f32x4*>(&sb[row * 64 + c0 + 4 * k]);
            acc[k] += ov * wsc;
        }
    }
    const float inv = 1.f / L;
    float* op = out + (size_t)(b * T_ + qt * 64 + row) * H_ + c0;
#pragma unroll
    for (int k = 0; k < 4; ++k)
        *reinterpret_cast<f32x4*>(&op[4 * k]) = acc[k] * inv;
}

// ---------------------------------------------------------------------------
// Fallback: single-pass attention (used only if ws too small for split-KV).
// ---------------------------------------------------------------------------
__global__ __launch_bounds__(256) void attn_kernel(
    const unsigned short* __restrict__ qkv, float* __restrict__ out) {

    const int b  = blockIdx.x >> 5;
    const int qt = blockIdx.x & 31;
    const int tid = threadIdx.x;
    const int w  = tid >> 6;
    const int l  = tid & 63;
    const int lg = l >> 4;
    const int lc = l & 15;

    __shared__ unsigned short Kl[64 * 64];
    __shared__ unsigned short Vt[64 * 64];
    __shared__ unsigned short Pl[4][16 * 64];

    const unsigned short* Qg = qkv;
    const unsigned short* Kg = qkv + (size_t)M_ * H_;
    const unsigned short* Vg = qkv + (size_t)2 * M_ * H_;

    const unsigned short* qrow = Qg + (size_t)(b * T_ + qt * 64 + w * 16 + lc) * H_;
    short8 qf[2];
#pragma unroll
    for (int ks = 0; ks < 2; ++ks)
        qf[ks] = make_frag(qrow + ks * 32 + lg * 4, qrow + ks * 32 + lg * 4 + 16);

    float m[4], lsum[4];
    f32x4 o[4];
#pragma unroll
    for (int r = 0; r < 4; ++r) { m[r] = -1e30f; lsum[r] = 0.f; }
#pragma unroll
    for (int t = 0; t < 4; ++t) o[t] = (f32x4)0.f;

    const int q_row_g = qt * 64 + w * 16 + lg * 4;

    for (int kv = 0; kv <= qt; ++kv) {
        __syncthreads();
#pragma unroll
        for (int rep = 0; rep < 2; ++rep) {
            const int idx = rep * 256 + tid;
            const int s   = idx >> 3;
            const int c16 = idx & 7;
            const size_t g = (size_t)(b * T_ + kv * 64 + s) * H_ + c16 * 8;
            short8 kvec = *reinterpret_cast<const short8*>(&Kg[g]);
            *reinterpret_cast<short8*>(&Kl[s * 64 + ((c16 ^ (s & 7)) << 3)]) = kvec;
        }
#pragma unroll
        for (int rep = 0; rep < 2; ++rep) {
            const int idx = rep * 256 + tid;
            const int s2  = idx >> 4;
            const int h0  = (idx & 15) * 4;
            const int s   = 2 * s2;
            const size_t g = (size_t)(b * T_ + kv * 64 + s) * H_ + h0;
            ushort4 v0 = *reinterpret_cast<const ushort4*>(&Vg[g]);
            ushort4 v1 = *reinterpret_cast<const ushort4*>(&Vg[g + H_]);
#pragma unroll
            for (int j = 0; j < 4; ++j) {
                const int h = h0 + j;
                unsigned int pk = (unsigned int)(&v0.x)[j] | ((unsigned int)(&v1.x)[j] << 16);
                *reinterpret_cast<unsigned int*>(&Vt[swz(h, s)]) = pk;
            }
        }
        __syncthreads();

        f32x4 sfrag[4];
#pragma unroll
        for (int st = 0; st < 4; ++st) {
            f32x4 accs = (f32x4)0.f;
#pragma unroll
            for (int ks = 0; ks < 2; ++ks) {
                const short8 bf = make_frag(&Kl[swz(st * 16 + lc, ks * 32 + lg * 4)],
                                            &Kl[swz(st * 16 + lc, ks * 32 + lg * 4 + 16)]);
                accs = __builtin_amdgcn_mfma_f32_16x16x32_bf16(qf[ks], bf, accs, 0, 0, 0);
            }
            sfrag[st] = accs;
        }

        const bool diag = (kv == qt);
        float p[4][4];
#pragma unroll
        for (int r = 0; r < 4; ++r) {
            float mx = -1e30f;
#pragma unroll
            for (int st = 0; st < 4; ++st) {
                float sv = sfrag[st][r] * LOG2E_SCALE;
                if (diag && (kv * 64 + st * 16 + lc) > (q_row_g + r)) sv = -1e30f;
                p[r][st] = sv;
                mx = fmaxf(mx, sv);
            }
#pragma unroll
            for (int d = 1; d < 16; d <<= 1) mx = fmaxf(mx, __shfl_xor(mx, d));

            const float mnew  = fmaxf(m[r], mx);
            const float alpha = exp2f(m[r] - mnew);
            float srow = 0.f;
#pragma unroll
            for (int st = 0; st < 4; ++st) {
                const float pv = exp2f(p[r][st] - mnew);
                p[r][st] = pv;
                srow += pv;
            }
#pragma unroll
            for (int d = 1; d < 16; d <<= 1) srow += __shfl_xor(srow, d);
            lsum[r] = lsum[r] * alpha + srow;
            m[r] = mnew;
#pragma unroll
            for (int ht = 0; ht < 4; ++ht) o[ht][r] *= alpha;
#pragma unroll
            for (int st = 0; st < 4; ++st)
                Pl[w][swz(lg * 4 + r, st * 16 + lc)] = f2bf(p[r][st]);
        }

#pragma unroll
        for (int ks = 0; ks < 2; ++ks) {
            const short8 pf = make_frag(&Pl[w][swz(lc, ks * 32 + lg * 4)],
                                        &Pl[w][swz(lc, ks * 32 + lg * 4 + 16)]);
#pragma unroll
            for (int ht = 0; ht < 4; ++ht) {
                const short8 vf = make_frag(&Vt[swz(ht * 16 + lc, ks * 32 + lg * 4)],
                                            &Vt[swz(ht * 16 + lc, ks * 32 + lg * 4 + 16)]);
                o[ht] = __builtin_amdgcn_mfma_f32_16x16x32_bf16(pf, vf, o[ht], 0, 0, 0);
            }
        }
    }

#pragma unroll
    for (int ht = 0; ht < 4; ++ht)
#pragma unroll
        for (int r = 0; r < 4; ++r) {
            const size_t oi = (size_t)(b * T_ + q_row_g + r) * H_ + ht * 16 + lc;
            out[oi] = o[ht][r] / lsum[r];
        }
}

extern "C" void kernel_launch(void* const* d_in, const int* in_sizes, int n_in,
                              void* d_out, int out_size, void* d_ws, size_t ws_size,
                              hipStream_t stream) {
    const float* x  = (const float*)d_in[0];
    const float* Wk = (const float*)d_in[1];
    const float* Wq = (const float*)d_in[2];
    const float* Wv = (const float*)d_in[3];

    const size_t qkvB = (size_t)3 * M_ * H_ * 2;          // 6,291,456
    const size_t WtB  = (size_t)3 * H_ * C_ * 2;          //   294,912
    unsigned short* qkv = (unsigned short*)d_ws;
    unsigned short* Wt  = (unsigned short*)((char*)d_ws + qkvB);
    float* part = (float*)((char*)d_ws + qkvB + WtB);
    float* out  = (float*)d_out;

    prep_w<<<dim3(144), dim3(256), 0, stream>>>(Wq, Wk, Wv, Wt);
    proj_kernel<<<dim3(M_ / 64), dim3(256), 0, stream>>>(x, Wt, qkv);

    const size_t need8  = qkvB + WtB + (size_t)(B_ * 80) * SEG_FLOATS * 4;
    const size_t need32 = qkvB + WtB + (size_t)(B_ * 32) * SEG_FLOATS * 4;
    if (ws_size >= need8) {
        attn_partial<8><<<dim3(B_ * 80), dim3(256), 0, stream>>>(qkv, part);
        attn_merge<8><<<dim3(B_ * 32), dim3(256), 0, stream>>>(part, out);
    } else if (ws_size >= need32) {
        attn_partial<32><<<dim3(B_ * 32), dim3(256), 0, stream>>>(qkv, part);
        attn_merge<32><<<dim3(B_ * 32), dim3(256), 0, stream>>>(part, out);
    } else {
        attn_kernel<<<dim3(B_ * 32), dim3(256), 0, stream>>>(qkv, out);
    }
}

// Round 4
// 64.336 us; speedup vs baseline: 4.5986x; 1.1748x over previous
//
#include <hip/hip_runtime.h>
#include <hip/hip_bf16.h>

typedef __attribute__((ext_vector_type(8))) short short8;
typedef __attribute__((ext_vector_type(4))) float f32x4;

#define B_  8
#define T_  2048
#define C_  768
#define H_  64
#define M_  (B_ * T_)   // 16384 rows

static __device__ __forceinline__ unsigned short f2bf(float f) {
    __hip_bfloat16 h = __float2bfloat16(f);
    return *reinterpret_cast<unsigned short*>(&h);
}

static __device__ __forceinline__ short8 make_frag(const unsigned short* p0, const unsigned short* p1) {
    const ushort4 a = *reinterpret_cast<const ushort4*>(p0);
    const ushort4 b = *reinterpret_cast<const ushort4*>(p1);
    short8 r;
    r[0] = (short)a.x; r[1] = (short)a.y; r[2] = (short)a.z; r[3] = (short)a.w;
    r[4] = (short)b.x; r[5] = (short)b.y; r[6] = (short)b.z; r[7] = (short)b.w;
    return r;
}

// XOR swizzle for LDS tiles with 64-ushort (128 B) rows (attn kernels).
static __device__ __forceinline__ int swz(int row, int u) {
    return row * 64 + ((((u) >> 3) ^ (row & 7)) << 3) + (u & 7);
}

// ---------------------------------------------------------------------------
// Kernel 0: W -> Wt  (transpose + fp32->bf16).  Wt[192][768] bf16.
// ---------------------------------------------------------------------------
__global__ __launch_bounds__(256) void prep_w(
    const float* __restrict__ Wq, const float* __restrict__ Wk, const float* __restrict__ Wv,
    unsigned short* __restrict__ Wt) {

    const int t   = threadIdx.x;
    const int mat = blockIdx.x / 48;
    const int kb  = blockIdx.x % 48;
    const int h   = t & 63;
    const int k0  = (kb * 4 + (t >> 6)) * 4;

    const float* Ws = (mat == 0) ? Wq : (mat == 1) ? Wk : Wv;
    ushort4 o;
    o.x = f2bf(Ws[(size_t)(k0 + 0) * H_ + h]);
    o.y = f2bf(Ws[(size_t)(k0 + 1) * H_ + h]);
    o.z = f2bf(Ws[(size_t)(k0 + 2) * H_ + h]);
    o.w = f2bf(Ws[(size_t)(k0 + 3) * H_ + h]);
    *reinterpret_cast<ushort4*>(&Wt[(size_t)(mat * 64 + h) * C_ + k0]) = o;
}

// ---------------------------------------------------------------------------
// Kernel 1: fused QKV projection (unchanged from round 3).
// ---------------------------------------------------------------------------
__global__ __launch_bounds__(256) void proj_kernel(
    const float* __restrict__ x, const unsigned short* __restrict__ Wt,
    unsigned short* __restrict__ qkv) {

    __shared__ unsigned short Als[4 * 12 * 512];   // 48 KB: [rt][kk][chunk*8]

    const int tid = threadIdx.x;
    const int w   = tid >> 6;
    const int l   = tid & 63;
    const int lg  = l >> 4;
    const int lc  = l & 15;
    const int row0 = blockIdx.x * 64;

    const int sr  = tid >> 2;
    const int so  = tid & 3;
    const int srt = sr >> 4;
    const int sr15 = sr & 15;
    const int sbase = (so * 16 + (sr15 ^ so)) * 8;

    f32x4 acc[4][3];
#pragma unroll
    for (int rt = 0; rt < 4; ++rt)
#pragma unroll
        for (int ct = 0; ct < 3; ++ct) acc[rt][ct] = (f32x4)0.f;

    const unsigned short* bbase[3];
#pragma unroll
    for (int ct = 0; ct < 3; ++ct)
        bbase[ct] = Wt + (size_t)(w * 48 + ct * 16 + lc) * C_ + lg * 8;

    for (int phase = 0; phase < 2; ++phase) {
        if (phase) __syncthreads();
#pragma unroll
        for (int g = 0; g < 3; ++g) {
            float4 fa[4][2];
#pragma unroll
            for (int jj = 0; jj < 4; ++jj) {
                const int j = g * 4 + jj;
                const float* xp = x + (size_t)(row0 + sr) * C_ + phase * 384 + j * 32 + so * 8;
                fa[jj][0] = *reinterpret_cast<const float4*>(xp);
                fa[jj][1] = *reinterpret_cast<const float4*>(xp + 4);
            }
#pragma unroll
            for (int jj = 0; jj < 4; ++jj) {
                const int j = g * 4 + jj;
                short8 v;
                v[0] = (short)f2bf(fa[jj][0].x); v[1] = (short)f2bf(fa[jj][0].y);
                v[2] = (short)f2bf(fa[jj][0].z); v[3] = (short)f2bf(fa[jj][0].w);
                v[4] = (short)f2bf(fa[jj][1].x); v[5] = (short)f2bf(fa[jj][1].y);
                v[6] = (short)f2bf(fa[jj][1].z); v[7] = (short)f2bf(fa[jj][1].w);
                *reinterpret_cast<short8*>(&Als[(srt * 12 + j) * 512 + sbase]) = v;
            }
        }
        __syncthreads();

        short8 bcur[3], bnxt[3];
#pragma unroll
        for (int ct = 0; ct < 3; ++ct)
            bcur[ct] = *reinterpret_cast<const short8*>(bbase[ct] + phase * 384);

#pragma unroll
        for (int kk = 0; kk < 12; ++kk) {
            if (kk < 11) {
#pragma unroll
                for (int ct = 0; ct < 3; ++ct)
                    bnxt[ct] = *reinterpret_cast<const short8*>(bbase[ct] + phase * 384 + (kk + 1) * 32);
            }
            short8 af[4];
#pragma unroll
            for (int rt = 0; rt < 4; ++rt)
                af[rt] = *reinterpret_cast<const short8*>(
                    &Als[(rt * 12 + kk) * 512 + (lg * 16 + (lc ^ lg)) * 8]);
#pragma unroll
            for (int rt = 0; rt < 4; ++rt)
#pragma unroll
                for (int ct = 0; ct < 3; ++ct)
                    acc[rt][ct] = __builtin_amdgcn_mfma_f32_16x16x32_bf16(af[rt], bcur[ct], acc[rt][ct], 0, 0, 0);
            if (kk < 11) {
#pragma unroll
                for (int ct = 0; ct < 3; ++ct) bcur[ct] = bnxt[ct];
            }
        }
    }

#pragma unroll
    for (int ct = 0; ct < 3; ++ct) {
        const int col = w * 48 + ct * 16 + lc;
        const int mat = col >> 6;
        const int h   = col & 63;
#pragma unroll
        for (int rt = 0; rt < 4; ++rt)
#pragma unroll
            for (int j = 0; j < 4; ++j) {
                const int grow = row0 + rt * 16 + lg * 4 + j;
                qkv[(size_t)mat * (M_ * H_) + (size_t)grow * H_ + h] = f2bf(acc[rt][ct][j]);
            }
    }
}

// ---------------------------------------------------------------------------
// Segment bookkeeping for split-KV flash attention (KV tiles of 64 rows).
// ---------------------------------------------------------------------------
#define SEG_FLOATS 4224
#define LOG2E_SCALE 0.18033688011112042f   // 0.125 * log2(e)

template<int SEG>
static __device__ __forceinline__ int segs_per_batch() { return SEG == 32 ? 32 : 80; }

template<int SEG>
static __device__ __forceinline__ void decode_seg(int r, int& qt, int& seg) {
    if (SEG == 32) { qt = r; seg = 0; return; }
    if (r < 8)       { qt = r;                seg = 0; }
    else if (r < 24) { qt = 8  + (r - 8) / 2; seg = (r - 8) & 1; }
    else if (r < 48) { qt = 16 + (r - 24) / 3; seg = (r - 24) % 3; }
    else             { qt = 24 + (r - 48) / 4; seg = (r - 48) & 3; }
}

template<int SEG>
static __device__ __forceinline__ int seg_prefix(int qt) {
    if (SEG == 32) return qt;
    if (qt < 8)  return qt;
    if (qt < 16) return 8  + 2 * (qt - 8);
    if (qt < 24) return 24 + 3 * (qt - 16);
    return 48 + 4 * (qt - 24);
}

// ---------------------------------------------------------------------------
// Kernel 2a: partial causal flash attention, SWAPPED-OPERAND form.
// S^T = mfma(K, Q): col = q (lane&15), row = s (4*lg+reg).  The S^T D-layout
// equals the B-frag layout of the PV mfma (col=q, k=s), so P^T feeds
// O^T = mfma(V^T, P^T) with zero cross-lane movement and no P LDS buffer.
// Softmax: in-lane tree over 16 s-values + 2 shfl_xor (16, 32) for all
// 16 q at once; alpha is one scalar per lane.
// ---------------------------------------------------------------------------
template<int SEG>
__global__ __launch_bounds__(256) void attn_partial(
    const unsigned short* __restrict__ qkv, float* __restrict__ part) {

    const int spb = segs_per_batch<SEG>();
    const int b   = blockIdx.x / spb;
    const int r_  = blockIdx.x % spb;
    int qt, seg;
    decode_seg<SEG>(r_, qt, seg);

    const int tid = threadIdx.x;
    const int w  = tid >> 6;
    const int l  = tid & 63;
    const int lg = l >> 4;
    const int lc = l & 15;

    __shared__ unsigned short Kl[64 * 64];   // K tile [s][h], swizzled
    __shared__ unsigned short Vt[64 * 64];   // V^T tile [h][s], swizzled

    const unsigned short* Qg = qkv;
    const unsigned short* Kg = qkv + (size_t)M_ * H_;
    const unsigned short* Vg = qkv + (size_t)2 * M_ * H_;

    // Q fragment (B-operand: col = q = w*16+lc, k = h)
    const unsigned short* qrow = Qg + (size_t)(b * T_ + qt * 64 + w * 16 + lc) * H_;
    short8 qf[2];
#pragma unroll
    for (int ks = 0; ks < 2; ++ks)
        qf[ks] = make_frag(qrow + ks * 32 + lg * 4, qrow + ks * 32 + lg * 4 + 16);

    float mval = -1e30f, lsum = 0.f;   // per-lane state for q = w*16+lc
    f32x4 oT[4];                       // O^T: [ht], h = ht*16+4*lg+reg, q = lc
#pragma unroll
    for (int t = 0; t < 4; ++t) oT[t] = (f32x4)0.f;

    const int q_glob = qt * 64 + w * 16 + lc;

    const int kv_beg = seg * SEG;
    const int kv_end = min(kv_beg + SEG, qt + 1);

    for (int kv = kv_beg; kv < kv_end; ++kv) {
        __syncthreads();
        // ---- stage K: 16B chunks, swizzled dest
#pragma unroll
        for (int rep = 0; rep < 2; ++rep) {
            const int idx = rep * 256 + tid;
            const int s   = idx >> 3;
            const int c16 = idx & 7;
            const size_t g = (size_t)(b * T_ + kv * 64 + s) * H_ + c16 * 8;
            short8 kvec = *reinterpret_cast<const short8*>(&Kg[g]);
            *reinterpret_cast<short8*>(&Kl[s * 64 + ((c16 ^ (s & 7)) << 3)]) = kvec;
        }
        // ---- stage V^T: paired-row u32 stores, swizzled dest
#pragma unroll
        for (int rep = 0; rep < 2; ++rep) {
            const int idx = rep * 256 + tid;
            const int s2  = idx >> 4;
            const int h0  = (idx & 15) * 4;
            const int s   = 2 * s2;
            const size_t g = (size_t)(b * T_ + kv * 64 + s) * H_ + h0;
            ushort4 v0 = *reinterpret_cast<const ushort4*>(&Vg[g]);
            ushort4 v1 = *reinterpret_cast<const ushort4*>(&Vg[g + H_]);
#pragma unroll
            for (int j = 0; j < 4; ++j) {
                const int h = h0 + j;
                unsigned int pk = (unsigned int)(&v0.x)[j] | ((unsigned int)(&v1.x)[j] << 16);
                *reinterpret_cast<unsigned int*>(&Vt[swz(h, s)]) = pk;
            }
        }
        __syncthreads();

        // ---- S^T = (K Q^T): st-tile rows s = st*16 + 4*lg + reg, col q = lc
        f32x4 sT[4];
#pragma unroll
        for (int st = 0; st < 4; ++st) {
            f32x4 accs = (f32x4)0.f;
#pragma unroll
            for (int ks = 0; ks < 2; ++ks) {
                const short8 kf = make_frag(&Kl[swz(st * 16 + lc, ks * 32 + lg * 4)],
                                            &Kl[swz(st * 16 + lc, ks * 32 + lg * 4 + 16)]);
                accs = __builtin_amdgcn_mfma_f32_16x16x32_bf16(kf, qf[ks], accs, 0, 0, 0);
            }
            sT[st] = accs;
        }

        // ---- in-register online softmax (log2 domain)
        float p[4][4];
#pragma unroll
        for (int st = 0; st < 4; ++st)
#pragma unroll
            for (int r = 0; r < 4; ++r)
                p[st][r] = sT[st][r] * LOG2E_SCALE;

        if (kv == qt) {
#pragma unroll
            for (int st = 0; st < 4; ++st)
#pragma unroll
                for (int r = 0; r < 4; ++r)
                    if ((kv * 64 + st * 16 + lg * 4 + r) > q_glob) p[st][r] = -1e30f;
        }

        float pm[4];
#pragma unroll
        for (int st = 0; st < 4; ++st)
            pm[st] = fmaxf(fmaxf(p[st][0], p[st][1]), fmaxf(p[st][2], p[st][3]));
        float pmax = fmaxf(fmaxf(pm[0], pm[1]), fmaxf(pm[2], pm[3]));
        pmax = fmaxf(pmax, __shfl_xor(pmax, 16));
        pmax = fmaxf(pmax, __shfl_xor(pmax, 32));

        const float mnew  = fmaxf(mval, pmax);
        const float alpha = exp2f(mval - mnew);
        mval = mnew;

        float ps[4];
#pragma unroll
        for (int st = 0; st < 4; ++st) {
#pragma unroll
            for (int r = 0; r < 4; ++r)
                p[st][r] = exp2f(p[st][r] - mnew);
            ps[st] = (p[st][0] + p[st][1]) + (p[st][2] + p[st][3]);
        }
        float srow = (ps[0] + ps[1]) + (ps[2] + ps[3]);
        srow += __shfl_xor(srow, 16);
        srow += __shfl_xor(srow, 32);
        lsum = lsum * alpha + srow;

#pragma unroll
        for (int ht = 0; ht < 4; ++ht) oT[ht] *= alpha;

        // ---- pack P^T -> bf16 B-frags (layout identity: D row s == B-frag k)
        short8 pb[2];
#pragma unroll
        for (int ks = 0; ks < 2; ++ks) {
#pragma unroll
            for (int r = 0; r < 4; ++r) {
                pb[ks][r]     = (short)f2bf(p[2 * ks][r]);
                pb[ks][r + 4] = (short)f2bf(p[2 * ks + 1][r]);
            }
        }

        // ---- O^T += V^T P^T
#pragma unroll
        for (int ks = 0; ks < 2; ++ks) {
#pragma unroll
            for (int ht = 0; ht < 4; ++ht) {
                const short8 vf = make_frag(&Vt[swz(ht * 16 + lc, ks * 32 + lg * 4)],
                                            &Vt[swz(ht * 16 + lc, ks * 32 + lg * 4 + 16)]);
                oT[ht] = __builtin_amdgcn_mfma_f32_16x16x32_bf16(vf, pb[ks], oT[ht], 0, 0, 0);
            }
        }
    }

    // ---- write partial: O^T regs land as [q][h] float4 stores
    float* base = part + (size_t)blockIdx.x * SEG_FLOATS;
#pragma unroll
    for (int ht = 0; ht < 4; ++ht)
        *reinterpret_cast<f32x4*>(&base[(w * 16 + lc) * 64 + ht * 16 + lg * 4]) = oT[ht];
    if (lg == 0) {
        base[4096 + w * 16 + lc] = mval;
        base[4160 + w * 16 + lc] = lsum;
    }
}

// ---------------------------------------------------------------------------
// Kernel 2b: merge segments, normalize, write output.
// ---------------------------------------------------------------------------
template<int SEG>
__global__ __launch_bounds__(256) void attn_merge(
    const float* __restrict__ part, float* __restrict__ out) {

    const int b  = blockIdx.x >> 5;
    const int qt = blockIdx.x & 31;
    const int nseg = (SEG == 32) ? 1 : (qt / 8 + 1);
    const int spb  = segs_per_batch<SEG>();
    const float* base0 = part + (size_t)(b * spb + seg_prefix<SEG>(qt)) * SEG_FLOATS;

    const int tid = threadIdx.x;
    const int row = tid >> 2;
    const int c0  = (tid & 3) * 16;

    float M = -1e30f;
    for (int s = 0; s < nseg; ++s)
        M = fmaxf(M, base0[(size_t)s * SEG_FLOATS + 4096 + row]);

    float L = 0.f;
    f32x4 acc[4];
#pragma unroll
    for (int k = 0; k < 4; ++k) acc[k] = (f32x4)0.f;

    for (int s = 0; s < nseg; ++s) {
        const float* sb = base0 + (size_t)s * SEG_FLOATS;
        const float wsc = exp2f(sb[4096 + row] - M);
        L += sb[4160 + row] * wsc;
#pragma unroll
        for (int k = 0; k < 4; ++k) {
            const f32x4 ov = *reinterpret_cast<const f32x4*>(&sb[row * 64 + c0 + 4 * k]);
            acc[k] += ov * wsc;
        }
    }
    const float inv = 1.f / L;
    float* op = out + (size_t)(b * T_ + qt * 64 + row) * H_ + c0;
#pragma unroll
    for (int k = 0; k < 4; ++k)
        *reinterpret_cast<f32x4*>(&op[4 * k]) = acc[k] * inv;
}

// ---------------------------------------------------------------------------
// Fallback: single-pass attention (used only if ws too small for split-KV).
// ---------------------------------------------------------------------------
__global__ __launch_bounds__(256) void attn_kernel(
    const unsigned short* __restrict__ qkv, float* __restrict__ out) {

    const int b  = blockIdx.x >> 5;
    const int qt = blockIdx.x & 31;
    const int tid = threadIdx.x;
    const int w  = tid >> 6;
    const int l  = tid & 63;
    const int lg = l >> 4;
    const int lc = l & 15;

    __shared__ unsigned short Kl[64 * 64];
    __shared__ unsigned short Vt[64 * 64];

    const unsigned short* Qg = qkv;
    const unsigned short* Kg = qkv + (size_t)M_ * H_;
    const unsigned short* Vg = qkv + (size_t)2 * M_ * H_;

    const unsigned short* qrow = Qg + (size_t)(b * T_ + qt * 64 + w * 16 + lc) * H_;
    short8 qf[2];
#pragma unroll
    for (int ks = 0; ks < 2; ++ks)
        qf[ks] = make_frag(qrow + ks * 32 + lg * 4, qrow + ks * 32 + lg * 4 + 16);

    float mval = -1e30f, lsum = 0.f;
    f32x4 oT[4];
#pragma unroll
    for (int t = 0; t < 4; ++t) oT[t] = (f32x4)0.f;

    const int q_glob = qt * 64 + w * 16 + lc;

    for (int kv = 0; kv <= qt; ++kv) {
        __syncthreads();
#pragma unroll
        for (int rep = 0; rep < 2; ++rep) {
            const int idx = rep * 256 + tid;
            const int s   = idx >> 3;
            const int c16 = idx & 7;
            const size_t g = (size_t)(b * T_ + kv * 64 + s) * H_ + c16 * 8;
            short8 kvec = *reinterpret_cast<const short8*>(&Kg[g]);
            *reinterpret_cast<short8*>(&Kl[s * 64 + ((c16 ^ (s & 7)) << 3)]) = kvec;
        }
#pragma unroll
        for (int rep = 0; rep < 2; ++rep) {
            const int idx = rep * 256 + tid;
            const int s2  = idx >> 4;
            const int h0  = (idx & 15) * 4;
            const int s   = 2 * s2;
            const size_t g = (size_t)(b * T_ + kv * 64 + s) * H_ + h0;
            ushort4 v0 = *reinterpret_cast<const ushort4*>(&Vg[g]);
            ushort4 v1 = *reinterpret_cast<const ushort4*>(&Vg[g + H_]);
#pragma unroll
            for (int j = 0; j < 4; ++j) {
                const int h = h0 + j;
                unsigned int pk = (unsigned int)(&v0.x)[j] | ((unsigned int)(&v1.x)[j] << 16);
                *reinterpret_cast<unsigned int*>(&Vt[swz(h, s)]) = pk;
            }
        }
        __syncthreads();

        f32x4 sT[4];
#pragma unroll
        for (int st = 0; st < 4; ++st) {
            f32x4 accs = (f32x4)0.f;
#pragma unroll
            for (int ks = 0; ks < 2; ++ks) {
                const short8 kf = make_frag(&Kl[swz(st * 16 + lc, ks * 32 + lg * 4)],
                                            &Kl[swz(st * 16 + lc, ks * 32 + lg * 4 + 16)]);
                accs = __builtin_amdgcn_mfma_f32_16x16x32_bf16(kf, qf[ks], accs, 0, 0, 0);
            }
            sT[st] = accs;
        }

        float p[4][4];
#pragma unroll
        for (int st = 0; st < 4; ++st)
#pragma unroll
            for (int r = 0; r < 4; ++r)
                p[st][r] = sT[st][r] * LOG2E_SCALE;

        if (kv == qt) {
#pragma unroll
            for (int st = 0; st < 4; ++st)
#pragma unroll
                for (int r = 0; r < 4; ++r)
                    if ((kv * 64 + st * 16 + lg * 4 + r) > q_glob) p[st][r] = -1e30f;
        }

        float pm[4];
#pragma unroll
        for (int st = 0; st < 4; ++st)
            pm[st] = fmaxf(fmaxf(p[st][0], p[st][1]), fmaxf(p[st][2], p[st][3]));
        float pmax = fmaxf(fmaxf(pm[0], pm[1]), fmaxf(pm[2], pm[3]));
        pmax = fmaxf(pmax, __shfl_xor(pmax, 16));
        pmax = fmaxf(pmax, __shfl_xor(pmax, 32));

        const float mnew  = fmaxf(mval, pmax);
        const float alpha = exp2f(mval - mnew);
        mval = mnew;

        float ps[4];
#pragma unroll
        for (int st = 0; st < 4; ++st) {
#pragma unroll
            for (int r = 0; r < 4; ++r)
                p[st][r] = exp2f(p[st][r] - mnew);
            ps[st] = (p[st][0] + p[st][1]) + (p[st][2] + p[st][3]);
        }
        float srow = (ps[0] + ps[1]) + (ps[2] + ps[3]);
        srow += __shfl_xor(srow, 16);
        srow += __shfl_xor(srow, 32);
        lsum = lsum * alpha + srow;

#pragma unroll
        for (int ht = 0; ht < 4; ++ht) oT[ht] *= alpha;

        short8 pb[2];
#pragma unroll
        for (int ks = 0; ks < 2; ++ks) {
#pragma unroll
            for (int r = 0; r < 4; ++r) {
                pb[ks][r]     = (short)f2bf(p[2 * ks][r]);
                pb[ks][r + 4] = (short)f2bf(p[2 * ks + 1][r]);
            }
        }

#pragma unroll
        for (int ks = 0; ks < 2; ++ks) {
#pragma unroll
            for (int ht = 0; ht < 4; ++ht) {
                const short8 vf = make_frag(&Vt[swz(ht * 16 + lc, ks * 32 + lg * 4)],
                                            &Vt[swz(ht * 16 + lc, ks * 32 + lg * 4 + 16)]);
                oT[ht] = __builtin_amdgcn_mfma_f32_16x16x32_bf16(vf, pb[ks], oT[ht], 0, 0, 0);
            }
        }
    }

    const float inv = 1.f / lsum;
    float* op = out + (size_t)(b * T_ + q_glob) * H_;
#pragma unroll
    for (int ht = 0; ht < 4; ++ht) {
        f32x4 v = oT[ht] * inv;
        *reinterpret_cast<f32x4*>(&op[ht * 16 + lg * 4]) = v;
    }
}

extern "C" void kernel_launch(void* const* d_in, const int* in_sizes, int n_in,
                              void* d_out, int out_size, void* d_ws, size_t ws_size,
                              hipStream_t stream) {
    const float* x  = (const float*)d_in[0];
    const float* Wk = (const float*)d_in[1];
    const float* Wq = (const float*)d_in[2];
    const float* Wv = (const float*)d_in[3];

    const size_t qkvB = (size_t)3 * M_ * H_ * 2;          // 6,291,456
    const size_t WtB  = (size_t)3 * H_ * C_ * 2;          //   294,912
    unsigned short* qkv = (unsigned short*)d_ws;
    unsigned short* Wt  = (unsigned short*)((char*)d_ws + qkvB);
    float* part = (float*)((char*)d_ws + qkvB + WtB);
    float* out  = (float*)d_out;

    prep_w<<<dim3(144), dim3(256), 0, stream>>>(Wq, Wk, Wv, Wt);
    proj_kernel<<<dim3(M_ / 64), dim3(256), 0, stream>>>(x, Wt, qkv);

    const size_t need8  = qkvB + WtB + (size_t)(B_ * 80) * SEG_FLOATS * 4;
    const size_t need32 = qkvB + WtB + (size_t)(B_ * 32) * SEG_FLOATS * 4;
    if (ws_size >= need8) {
        attn_partial<8><<<dim3(B_ * 80), dim3(256), 0, stream>>>(qkv, part);
        attn_merge<8><<<dim3(B_ * 32), dim3(256), 0, stream>>>(part, out);
    } else if (ws_size >= need32) {
        attn_partial<32><<<dim3(B_ * 32), dim3(256), 0, stream>>>(qkv, part);
        attn_merge<32><<<dim3(B_ * 32), dim3(256), 0, stream>>>(part, out);
    } else {
        attn_kernel<<<dim3(B_ * 32), dim3(256), 0, stream>>>(qkv, out);
    }
}